// Round 5
// baseline (686.098 us; speedup 1.0000x reference)
//
#include <hip/hip_runtime.h>
#include <cmath>

#define NPTS   1048576
#define NLVL   16
#define T      (1u << 19)
#define TMASK  (T - 1u)
#define P1     2654435761u
#define P2     805459861u

typedef float v2f __attribute__((ext_vector_type(2)));
typedef float v4f __attribute__((ext_vector_type(4)));

// ---------- common per-point preamble ----------
#define PREAMBLE                                                             \
    const int n = blockIdx.x * 256 + threadIdx.x;                            \
    const float px = __builtin_nontemporal_load(x + 3 * (size_t)n + 0);      \
    const float py = __builtin_nontemporal_load(x + 3 * (size_t)n + 1);      \
    const float pz = __builtin_nontemporal_load(x + 3 * (size_t)n + 2);      \
    const float xs0 = px * rf, xs1 = py * rf, xs2 = pz * rf;                 \
    const float f0 = floorf(xs0), f1 = floorf(xs1), f2 = floorf(xs2);        \
    const float w0 = xs0 - f0, w1 = xs1 - f1, w2 = xs2 - f2;                 \
    const uint32_t i0 = (uint32_t)f0;                                        \
    const uint32_t i1 = (uint32_t)f1;                                        \
    const uint32_t i2 = (uint32_t)f2;                                        \
    const uint32_t A0 = i0,      A1 = i0 + 1u;                               \
    const uint32_t B0 = i1 * P1, B1 = B0 + P1;                               \
    const uint32_t C0 = i2 * P2, C1 = C0 + P2;                               \
    const uint32_t h[8] = {                                                  \
        (A0 ^ B0 ^ C0) & TMASK, (A0 ^ B0 ^ C1) & TMASK,                      \
        (A0 ^ B1 ^ C0) & TMASK, (A0 ^ B1 ^ C1) & TMASK,                      \
        (A1 ^ B0 ^ C0) & TMASK, (A1 ^ B0 ^ C1) & TMASK,                      \
        (A1 ^ B1 ^ C0) & TMASK, (A1 ^ B1 ^ C1) & TMASK };                    \
    const float u0 = 1.0f - w0, u1 = 1.0f - w1, u2 = 1.0f - w2;              \
    const float wt[8] = {                                                    \
        (u0 * u1) * u2, (u0 * u1) * w2, (u0 * w1) * u2, (u0 * w1) * w2,      \
        (w0 * u1) * u2, (w0 * u1) * w2, (w0 * w1) * u2, (w0 * w1) * w2 };

// One-pass kernel (small-footprint levels): full-range gather, NT store to ws.
__global__ __launch_bounds__(256) void hashgrid_lvl1(
    const float* __restrict__ x,
    const float* __restrict__ tb,
    float* __restrict__ wsl,
    float rf)
{
    PREAMBLE
    float a0 = 0.f, a1 = 0.f;
#pragma unroll
    for (int c = 0; c < 8; ++c) {
        const float2 g = *(const float2*)(tb + 2 * (size_t)h[c]);
        a0 += wt[c] * g.x;
        a1 += wt[c] * g.y;
    }
    v2f r; r.x = a0; r.y = a1;
    __builtin_nontemporal_store(r, (v2f*)(wsl + (size_t)n * 2));
}

// Range-pass kernel (full-table levels): gathers only corners whose hash lies
// in [lo,hi) so the hot table slice (2 MiB) is strictly L2-resident.
// addin=1 -> accumulate onto the partial already in ws.
__global__ __launch_bounds__(256) void hashgrid_lvl_range(
    const float* __restrict__ x,
    const float* __restrict__ tb,
    float* __restrict__ wsl,
    float rf,
    uint32_t lo, uint32_t hi, int addin)
{
    PREAMBLE
    float a0 = 0.f, a1 = 0.f;
    if (addin) {
        const v2f p = __builtin_nontemporal_load((const v2f*)(wsl + (size_t)n * 2));
        a0 = p.x; a1 = p.y;
    }
#pragma unroll
    for (int c = 0; c < 8; ++c) {
        if (h[c] >= lo && h[c] < hi) {
            const float2 g = *(const float2*)(tb + 2 * (size_t)h[c]);
            a0 += wt[c] * g.x;
            a1 += wt[c] * g.y;
        }
    }
    v2f r; r.x = a0; r.y = a1;
    __builtin_nontemporal_store(r, (v2f*)(wsl + (size_t)n * 2));
}

// ws [L][N][2] -> out [N][L*2]. NT loads (ws is L3-resident, never reused),
// cached stores so L2 merges each thread's 8x16B into one full line.
__global__ __launch_bounds__(256) void hashgrid_transpose(
    const float* __restrict__ ws,
    float* __restrict__ out)
{
    const int n = blockIdx.x * 256 + threadIdx.x;
    float acc[2 * NLVL];
#pragma unroll
    for (int l = 0; l < NLVL; ++l) {
        const v2f g = __builtin_nontemporal_load(
            (const v2f*)(ws + ((size_t)l << 21) + (size_t)n * 2));
        acc[2 * l + 0] = g.x;
        acc[2 * l + 1] = g.y;
    }
    v4f* op = (v4f*)(out + (size_t)n * 32);
#pragma unroll
    for (int k = 0; k < 8; ++k) {
        v4f v; v.x = acc[4*k]; v.y = acc[4*k+1]; v.z = acc[4*k+2]; v.w = acc[4*k+3];
        op[k] = v;
    }
}

// Fallback (no usable ws): original one-kernel-per-level direct-out path.
__global__ __launch_bounds__(256) void hashgrid_lvl_direct(
    const float* __restrict__ x,
    const float* __restrict__ tb,
    float* __restrict__ outl,
    float rf)
{
    PREAMBLE
    float a0 = 0.f, a1 = 0.f;
#pragma unroll
    for (int c = 0; c < 8; ++c) {
        const float2 g = *(const float2*)(tb + 2 * (size_t)h[c]);
        a0 += wt[c] * g.x;
        a1 += wt[c] * g.y;
    }
    outl[(size_t)n * 32 + 0] = a0;
    outl[(size_t)n * 32 + 1] = a1;
}

extern "C" void kernel_launch(void* const* d_in, const int* in_sizes, int n_in,
                              void* d_out, int out_size, void* d_ws, size_t ws_size,
                              hipStream_t stream) {
    const float* x     = (const float*)d_in[0];
    const float* table = (const float*)d_in[1];
    float* out         = (float*)d_out;
    float* ws          = (float*)d_ws;

    // Reproduce Python's RESOLUTIONS bit-exactly using the same libm
    // (volatile fn pointers stop clang from folding/strength-reducing pow).
    double (*volatile p_log)(double)          = log;
    double (*volatile p_exp)(double)          = exp;
    double (*volatile p_pow)(double, double)  = pow;
    double (*volatile p_floor)(double)        = floor;

    const double b = p_exp((p_log(2048.0) - p_log(16.0)) / 15.0);

    const bool use_ws = ws_size >= (size_t)NLVL * NPTS * 2 * sizeof(float);
    const int grid = NPTS / 256;

    for (int l = 0; l < NLVL; ++l) {
        const int res = (int)p_floor(16.0 * p_pow(b, (double)l));
        const float rf = (float)res;
        const float* tb = table + ((size_t)l << 20);

        if (!use_ws) {
            hashgrid_lvl_direct<<<grid, 256, 0, stream>>>(x, tb, out + 2 * l, rf);
            continue;
        }
        float* wsl = ws + ((size_t)l << 21);
        if (l <= 4) {
            // footprint (res+1)^3 lines < ~3.8 MiB: single pass, L2-resident
            hashgrid_lvl1<<<grid, 256, 0, stream>>>(x, tb, wsl, rf);
        } else {
            // full-table levels: two 2 MiB hash-range passes
            hashgrid_lvl_range<<<grid, 256, 0, stream>>>(x, tb, wsl, rf, 0u,    T/2, 0);
            hashgrid_lvl_range<<<grid, 256, 0, stream>>>(x, tb, wsl, rf, T/2,  T,   1);
        }
    }
    if (use_ws) {
        hashgrid_transpose<<<grid, 256, 0, stream>>>(ws, out);
    }
}

// Round 6
// 564.402 us; speedup vs baseline: 1.2156x; 1.2156x over previous
//
#include <hip/hip_runtime.h>
#include <cmath>

#define NPTS   1048576
#define NLVL   16
#define NLOW   5                 // levels 0..4 inlined in the final kernel
#define NHEAVY (NLVL - NLOW)     // levels 5..15 via ws
#define T      (1u << 19)
#define TMASK  (T - 1u)
#define P1     2654435761u
#define P2     805459861u

typedef float v2f __attribute__((ext_vector_type(2)));
typedef float v4f __attribute__((ext_vector_type(4)));

struct Corners { uint32_t h[8]; float wt[8]; };

// Must match fp32 reference arithmetic exactly (same ops/order as the
// passing R1-R5 kernels).
__device__ __forceinline__ Corners mk_corners(float px, float py, float pz, float rf) {
    Corners cc;
    const float xs0 = px * rf, xs1 = py * rf, xs2 = pz * rf;
    const float f0 = floorf(xs0), f1 = floorf(xs1), f2 = floorf(xs2);
    const float w0 = xs0 - f0, w1 = xs1 - f1, w2 = xs2 - f2;
    const uint32_t i0 = (uint32_t)f0, i1 = (uint32_t)f1, i2 = (uint32_t)f2;
    const uint32_t A0 = i0,      A1 = i0 + 1u;
    const uint32_t B0 = i1 * P1, B1 = B0 + P1;
    const uint32_t C0 = i2 * P2, C1 = C0 + P2;
    cc.h[0] = (A0 ^ B0 ^ C0) & TMASK;  cc.h[1] = (A0 ^ B0 ^ C1) & TMASK;
    cc.h[2] = (A0 ^ B1 ^ C0) & TMASK;  cc.h[3] = (A0 ^ B1 ^ C1) & TMASK;
    cc.h[4] = (A1 ^ B0 ^ C0) & TMASK;  cc.h[5] = (A1 ^ B0 ^ C1) & TMASK;
    cc.h[6] = (A1 ^ B1 ^ C0) & TMASK;  cc.h[7] = (A1 ^ B1 ^ C1) & TMASK;
    const float u0 = 1.0f - w0, u1 = 1.0f - w1, u2 = 1.0f - w2;
    cc.wt[0] = (u0 * u1) * u2;  cc.wt[1] = (u0 * u1) * w2;
    cc.wt[2] = (u0 * w1) * u2;  cc.wt[3] = (u0 * w1) * w2;
    cc.wt[4] = (w0 * u1) * u2;  cc.wt[5] = (w0 * u1) * w2;
    cc.wt[6] = (w0 * w1) * u2;  cc.wt[7] = (w0 * w1) * w2;
    return cc;
}

// Heavy level (full-table footprint): 2 points per thread for 16 gathers in
// flight per wave + amortized x/store overhead. Dense NT ws stores.
__global__ __launch_bounds__(256) void hashgrid_lvl2pt(
    const float* __restrict__ x,
    const float* __restrict__ tb,     // table + lvl*T*F
    float* __restrict__ wsl,          // ws slice [N][2]
    float rf)
{
    const int t  = blockIdx.x * 256 + threadIdx.x;
    const int n0 = t;
    const int n1 = t + NPTS / 2;

    const float p0x = __builtin_nontemporal_load(x + 3 * (size_t)n0 + 0);
    const float p0y = __builtin_nontemporal_load(x + 3 * (size_t)n0 + 1);
    const float p0z = __builtin_nontemporal_load(x + 3 * (size_t)n0 + 2);
    const float p1x = __builtin_nontemporal_load(x + 3 * (size_t)n1 + 0);
    const float p1y = __builtin_nontemporal_load(x + 3 * (size_t)n1 + 1);
    const float p1z = __builtin_nontemporal_load(x + 3 * (size_t)n1 + 2);

    const Corners c0 = mk_corners(p0x, p0y, p0z, rf);
    const Corners c1 = mk_corners(p1x, p1y, p1z, rf);

    float a00 = 0.f, a01 = 0.f, a10 = 0.f, a11 = 0.f;
#pragma unroll
    for (int c = 0; c < 8; ++c) {
        const float2 g0 = *(const float2*)(tb + 2 * (size_t)c0.h[c]);
        const float2 g1 = *(const float2*)(tb + 2 * (size_t)c1.h[c]);
        a00 += c0.wt[c] * g0.x;  a01 += c0.wt[c] * g0.y;
        a10 += c1.wt[c] * g1.x;  a11 += c1.wt[c] * g1.y;
    }
    v2f r0; r0.x = a00; r0.y = a01;
    v2f r1; r1.x = a10; r1.y = a11;
    __builtin_nontemporal_store(r0, (v2f*)(wsl + (size_t)n0 * 2));
    __builtin_nontemporal_store(r1, (v2f*)(wsl + (size_t)n1 * 2));
}

// Final kernel: computes levels 0..4 inline (tables total ~2.6 MB, cache-
// trivial), merges with ws levels 5..15, writes out [N][32] with cached
// full-line stores.
__global__ __launch_bounds__(256) void hashgrid_final(
    const float* __restrict__ x,
    const float* __restrict__ table,
    const float* __restrict__ ws,
    float* __restrict__ out,
    float r0, float r1, float r2, float r3, float r4)
{
    const int n = blockIdx.x * 256 + threadIdx.x;
    float acc[2 * NLVL];

    // heavy levels from ws (NT: read-once, L3-resident)
#pragma unroll
    for (int j = 0; j < NHEAVY; ++j) {
        const v2f g = __builtin_nontemporal_load(
            (const v2f*)(ws + ((size_t)j << 21) + (size_t)n * 2));
        acc[2 * (NLOW + j) + 0] = g.x;
        acc[2 * (NLOW + j) + 1] = g.y;
    }

    const float px = __builtin_nontemporal_load(x + 3 * (size_t)n + 0);
    const float py = __builtin_nontemporal_load(x + 3 * (size_t)n + 1);
    const float pz = __builtin_nontemporal_load(x + 3 * (size_t)n + 2);

    const float rs[NLOW] = {r0, r1, r2, r3, r4};
#pragma unroll
    for (int l = 0; l < NLOW; ++l) {
        const Corners cc = mk_corners(px, py, pz, rs[l]);
        const float* tb = table + ((size_t)l << 20);
        float a0 = 0.f, a1 = 0.f;
#pragma unroll
        for (int c = 0; c < 8; ++c) {
            const float2 g = *(const float2*)(tb + 2 * (size_t)cc.h[c]);
            a0 += cc.wt[c] * g.x;
            a1 += cc.wt[c] * g.y;
        }
        acc[2 * l + 0] = a0;
        acc[2 * l + 1] = a1;
    }

    v4f* op = (v4f*)(out + (size_t)n * 32);
#pragma unroll
    for (int k = 0; k < 8; ++k) {
        v4f v; v.x = acc[4*k]; v.y = acc[4*k+1]; v.z = acc[4*k+2]; v.w = acc[4*k+3];
        op[k] = v;   // cached store -> L2 merges into full 128B lines
    }
}

// Fallback (no usable ws): one kernel per level, direct strided-out writes.
__global__ __launch_bounds__(256) void hashgrid_lvl_direct(
    const float* __restrict__ x,
    const float* __restrict__ tb,
    float* __restrict__ outl,
    float rf)
{
    const int n = blockIdx.x * 256 + threadIdx.x;
    const float px = __builtin_nontemporal_load(x + 3 * (size_t)n + 0);
    const float py = __builtin_nontemporal_load(x + 3 * (size_t)n + 1);
    const float pz = __builtin_nontemporal_load(x + 3 * (size_t)n + 2);
    const Corners cc = mk_corners(px, py, pz, rf);
    float a0 = 0.f, a1 = 0.f;
#pragma unroll
    for (int c = 0; c < 8; ++c) {
        const float2 g = *(const float2*)(tb + 2 * (size_t)cc.h[c]);
        a0 += cc.wt[c] * g.x;
        a1 += cc.wt[c] * g.y;
    }
    outl[(size_t)n * 32 + 0] = a0;
    outl[(size_t)n * 32 + 1] = a1;
}

extern "C" void kernel_launch(void* const* d_in, const int* in_sizes, int n_in,
                              void* d_out, int out_size, void* d_ws, size_t ws_size,
                              hipStream_t stream) {
    const float* x     = (const float*)d_in[0];
    const float* table = (const float*)d_in[1];
    float* out         = (float*)d_out;
    float* ws          = (float*)d_ws;

    // Reproduce Python's RESOLUTIONS bit-exactly using the same libm
    // (volatile fn pointers stop clang from folding/strength-reducing pow).
    double (*volatile p_log)(double)          = log;
    double (*volatile p_exp)(double)          = exp;
    double (*volatile p_pow)(double, double)  = pow;
    double (*volatile p_floor)(double)        = floor;

    const double b = p_exp((p_log(2048.0) - p_log(16.0)) / 15.0);
    float rf[NLVL];
    for (int l = 0; l < NLVL; ++l)
        rf[l] = (float)(int)p_floor(16.0 * p_pow(b, (double)l));

    const bool use_ws = ws_size >= (size_t)NHEAVY * NPTS * 2 * sizeof(float);

    if (!use_ws) {
        for (int l = 0; l < NLVL; ++l)
            hashgrid_lvl_direct<<<NPTS / 256, 256, 0, stream>>>(
                x, table + ((size_t)l << 20), out + 2 * l, rf[l]);
        return;
    }

    // heavy levels 5..15 -> ws slices 0..10
    for (int l = NLOW; l < NLVL; ++l) {
        hashgrid_lvl2pt<<<NPTS / 512, 256, 0, stream>>>(
            x, table + ((size_t)l << 20), ws + ((size_t)(l - NLOW) << 21), rf[l]);
    }
    hashgrid_final<<<NPTS / 256, 256, 0, stream>>>(
        x, table, ws, out, rf[0], rf[1], rf[2], rf[3], rf[4]);
}